// Round 11
// baseline (1650.077 us; speedup 1.0000x reference)
//
#include <hip/hip_runtime.h>
#include <hip/hip_bf16.h>

// Problem constants (from reference)
#define N_NODES 50000
#define N_EDGES 150000
#define NODE_IN 64
#define EDGE_IN 16
#define DD 32          // node feature dim
#define EHID 128       // edge-network hidden
#define STEPS 3

// Device-verified harness dtypes: float inputs fp32, edge_index int32, output fp32.
__device__ __forceinline__ ushort f2b(float f) {
    __hip_bfloat16 b = __float2bfloat16(f);   // RNE
    return *reinterpret_cast<ushort*>(&b);
}

typedef __bf16 bf16x8 __attribute__((ext_vector_type(8)));
typedef float  f32x4  __attribute__((ext_vector_type(4)));

#define LDA  136   // As leading dim (ushorts): 272B rows, 16B-aligned, bank-skewed
#define HPAD 36    // Hs leading dim (floats): 144B rows

// ---------------------------------------------------------------------------
// prep: repack We2/We1 into MFMA-fragment-major bf16 buffers.
//  we2B unit u = ((bn*4+nt)*4+kt)*64 + lane, 8 ushorts:
//    bf16(We2[kt*32+(lane>>4)*8+j][bn*64+nt*16+(lane&15)])
//  we1B unit u = nt*64 + lane: bf16(We1[(lane>>4)*8+j][nt*16+(lane&15)]), k>=16 -> 0
__global__ __launch_bounds__(256) void prep(const float* __restrict__ we2,
                                            const float* __restrict__ we1,
                                            ushort* __restrict__ we2B,
                                            ushort* __restrict__ we1B) {
    int i = blockIdx.x * 256 + threadIdx.x;
    if (i < 16384) {
        int l = i & 63, f = i >> 6;           // f = bn*16 + nt*4 + kt
        int kt = f & 3, nt = (f >> 2) & 3, bn = f >> 4;
        int lr = l & 15, lg = l >> 4;
        int n = bn * 64 + nt * 16 + lr;
        int k0 = kt * 32 + lg * 8;
        ushort tmp[8];
#pragma unroll
        for (int j = 0; j < 8; ++j) tmp[j] = f2b(we2[(size_t)(k0 + j) * 1024 + n]);
        *(uint4*)(we2B + (size_t)i * 8) = *(uint4*)tmp;
    } else if (i < 16384 + 512) {
        int u = i - 16384;
        int l = u & 63, nt = u >> 6;
        int lr = l & 15, lg = l >> 4;
        int n = nt * 16 + lr;
        ushort tmp[8];
#pragma unroll
        for (int j = 0; j < 8; ++j) {
            int k = lg * 8 + j;
            tmp[j] = (k < EDGE_IN) ? f2b(we1[(size_t)k * EHID + n]) : (ushort)0;
        }
        *(uint4*)(we1B + (size_t)u * 8) = *(uint4*)tmp;
    }
}

// ---------------------------------------------------------------------------
// node_init: thread = node; Wn transposed in LDS so dots are contiguous float4.
__global__ __launch_bounds__(256) void node_init(const float* __restrict__ x,
                                                 const float* __restrict__ Wn,
                                                 const float* __restrict__ bn,
                                                 float* __restrict__ h) {
    __shared__ float Wnt[DD * NODE_IN];   // [o][i], 8 KB
    __shared__ float bns[DD];
    int t = threadIdx.x;
    for (int i = t; i < NODE_IN * DD; i += 256) Wnt[(i & 31) * NODE_IN + (i >> 5)] = Wn[i];
    if (t < DD) bns[t] = bn[t];
    __syncthreads();
    int n = blockIdx.x * 256 + t;
    if (n >= N_NODES) return;
    float xr[NODE_IN];
    const float4* xp = (const float4*)(x + (size_t)n * NODE_IN);
#pragma unroll
    for (int q = 0; q < NODE_IN / 4; ++q) *(float4*)&xr[q * 4] = xp[q];
    float out[DD];
#pragma unroll
    for (int o = 0; o < DD; ++o) {
        const float4* wr = (const float4*)(Wnt + o * NODE_IN);
        float s = bns[o];
#pragma unroll
        for (int q = 0; q < NODE_IN / 4; ++q) {
            float4 wv = wr[q];
            s += xr[q * 4] * wv.x + xr[q * 4 + 1] * wv.y + xr[q * 4 + 2] * wv.z + xr[q * 4 + 3] * wv.w;
        }
        out[o] = fmaxf(s, 0.f);
    }
    float4* hp = (float4*)(h + (size_t)n * DD);
#pragma unroll
    for (int q = 0; q < DD / 4; ++q) hp[q] = *(float4*)&out[q * 4];
}

// ---------------------------------------------------------------------------
// fused_msg: block = 256 edges, 4 m-tiles per wave (halves per-edge L2 B-traffic
// vs 128-edge blocks). B-frags stream from L2 (fragment-major we2B); main loop
// is barrier-free. Verified gfx950 16x16x32 mappings:
// A[m=lane&15][k=(lane>>4)*8+j], B[n=lane&15][k=same], D[row=(lane>>4)*4+r][col=lane&15].
__global__ __launch_bounds__(256, 2) void fused_msg(const float* __restrict__ ea,
                                                    const ushort* __restrict__ we1B,
                                                    const float* __restrict__ be1,
                                                    const ushort* __restrict__ we2B,
                                                    const float* __restrict__ be2,
                                                    const int* __restrict__ ei,
                                                    const float* __restrict__ h,
                                                    float* __restrict__ agg) {
    __shared__ __attribute__((aligned(16))) ushort AsHs[256 * LDA];  // 69632 B
    __shared__ float b1s[EHID];                                      // 512 B
    __shared__ float be2s[DD * DD];                                  // 4096 B
    float* Hs = (float*)AsHs;       // [256][HPAD] fp32 view (36864 B), reused

    int t = threadIdx.x;
    if (t < EHID) b1s[t] = be1[t];
    for (int i = t; i < DD * DD; i += 256) be2s[i] = be2[i];

    int w = t >> 6, l = t & 63;
    int lr = l & 15, lg = l >> 4;

    // ---- Phase A input fragments straight from global ----
    bf16x8 afe[4];
#pragma unroll
    for (int mi = 0; mi < 4; ++mi) {
        int e = blockIdx.x * 256 + (w * 4 + mi) * 16 + lr;
        ushort tmp[8] = {0, 0, 0, 0, 0, 0, 0, 0};
        if (lg < 2 && e < N_EDGES) {
            const float4* p = (const float4*)(ea + (size_t)e * EDGE_IN + lg * 8);
            float4 a = p[0], b = p[1];
            tmp[0] = f2b(a.x); tmp[1] = f2b(a.y); tmp[2] = f2b(a.z); tmp[3] = f2b(a.w);
            tmp[4] = f2b(b.x); tmp[5] = f2b(b.y); tmp[6] = f2b(b.z); tmp[7] = f2b(b.w);
        }
        afe[mi] = *(bf16x8*)tmp;
    }
    __syncthreads();   // (1) b1s ready

    // ---- Phase A: g = relu(ea@We1+be1) via MFMA -> bf16 As[256][128] ----
#pragma unroll
    for (int nt = 0; nt < 8; ++nt) {
        bf16x8 bfe = *(const bf16x8*)(we1B + (size_t)((nt << 6) + l) * 8);
        int kh = nt * 16 + lr;
        float bb = b1s[kh];
#pragma unroll
        for (int mi = 0; mi < 4; ++mi) {
            f32x4 acc = (f32x4){0.f, 0.f, 0.f, 0.f};
            acc = __builtin_amdgcn_mfma_f32_16x16x32_bf16(afe[mi], bfe, acc, 0, 0, 0);
#pragma unroll
            for (int r = 0; r < 4; ++r)
                AsHs[((w * 4 + mi) * 16 + lg * 4 + r) * LDA + kh] = f2b(fmaxf(acc[r] + bb, 0.f));
        }
    }
    __syncthreads();   // (2) As complete

    bf16x8 afrag[4][4];
#pragma unroll
    for (int mi = 0; mi < 4; ++mi)
#pragma unroll
        for (int kt = 0; kt < 4; ++kt)
            afrag[mi][kt] = *(const bf16x8*)(&AsHs[((w * 4 + mi) * 16 + lr) * LDA + kt * 32 + lg * 8]);
    __syncthreads();   // (3) As reads done -> reuse as Hs

    // ---- Gather h[src]: thread t owns edge row t ----
    {
        int e = blockIdx.x * 256 + t;
        float4* hd = (float4*)(Hs + t * HPAD);
        if (e < N_EDGES) {
            int src = ei[e];
            const float4* hr = (const float4*)(h + (size_t)src * DD);
#pragma unroll
            for (int q = 0; q < 8; ++q) hd[q] = hr[q];
        } else {
            float4 z = make_float4(0.f, 0.f, 0.f, 0.f);
#pragma unroll
            for (int q = 0; q < 8; ++q) hd[q] = z;
        }
    }
    __syncthreads();   // (4) Hs ready — last barrier

    float m_acc[4][4][2];
#pragma unroll
    for (int mi = 0; mi < 4; ++mi)
#pragma unroll
        for (int r = 0; r < 4; ++r) { m_acc[mi][r][0] = 0.f; m_acc[mi][r][1] = 0.f; }

    // ---- Main loop: 16 column tiles, B direct from L2, barrier-free ----
    for (int bn = 0; bn < 16; ++bn) {
        float bv[4];
#pragma unroll
        for (int nt = 0; nt < 4; ++nt) bv[nt] = be2s[bn * 64 + nt * 16 + lr];

        f32x4 acc[4][4];
#pragma unroll
        for (int mi = 0; mi < 4; ++mi)
#pragma unroll
            for (int nt = 0; nt < 4; ++nt) acc[mi][nt] = (f32x4){0.f, 0.f, 0.f, 0.f};

#pragma unroll
        for (int kt = 0; kt < 4; ++kt) {
            const ushort* base = we2B + (size_t)((bn * 16 + kt) * 64 + l) * 8;
            bf16x8 b0 = *(const bf16x8*)(base);
            bf16x8 b1 = *(const bf16x8*)(base + 2048);
            bf16x8 b2 = *(const bf16x8*)(base + 4096);
            bf16x8 b3 = *(const bf16x8*)(base + 6144);
#pragma unroll
            for (int mi = 0; mi < 4; ++mi) {
                acc[mi][0] = __builtin_amdgcn_mfma_f32_16x16x32_bf16(afrag[mi][kt], b0, acc[mi][0], 0, 0, 0);
                acc[mi][1] = __builtin_amdgcn_mfma_f32_16x16x32_bf16(afrag[mi][kt], b1, acc[mi][1], 0, 0, 0);
                acc[mi][2] = __builtin_amdgcn_mfma_f32_16x16x32_bf16(afrag[mi][kt], b2, acc[mi][2], 0, 0, 0);
                acc[mi][3] = __builtin_amdgcn_mfma_f32_16x16x32_bf16(afrag[mi][kt], b3, acc[mi][3], 0, 0, 0);
            }
        }

        // Fold: col=bn*64+nt*16+lr -> i=2bn+(nt>>1), o=16*(nt&1)+lr
#pragma unroll
        for (int mi = 0; mi < 4; ++mi) {
#pragma unroll
            for (int r = 0; r < 4; ++r) {
                int row = (w * 4 + mi) * 16 + lg * 4 + r;
                float2 hv = *(const float2*)(Hs + row * HPAD + bn * 2);
#pragma unroll
                for (int nt = 0; nt < 4; ++nt) {
                    float hi = (nt >> 1) ? hv.y : hv.x;
                    m_acc[mi][r][nt & 1] += hi * (acc[mi][nt][r] + bv[nt]);
                }
            }
        }
    }

    // ---- Scatter: agg[dst] += m ----
#pragma unroll
    for (int mi = 0; mi < 4; ++mi) {
#pragma unroll
        for (int r = 0; r < 4; ++r) {
            int le = (w * 4 + mi) * 16 + lg * 4 + r;
            int e = blockIdx.x * 256 + le;
            if (e < N_EDGES) {
                int dst = ei[N_EDGES + e];
                float* ar = agg + (size_t)dst * DD;
                atomicAdd(ar + lr,      m_acc[mi][r][0]);
                atomicAdd(ar + lr + 16, m_acc[mi][r][1]);
            }
        }
    }
}

// ---------------------------------------------------------------------------
// conv + GRU: thread = node; Wroot transposed in LDS; all dots contiguous float4.
// Zeroes agg for the next step.
__global__ __launch_bounds__(256) void conv_gru(float* __restrict__ agg,
                                                float* __restrict__ h,
                                                const float* __restrict__ Wroot,
                                                const float* __restrict__ bconv,
                                                const float* __restrict__ Wih,
                                                const float* __restrict__ Whh,
                                                const float* __restrict__ bih,
                                                const float* __restrict__ bhh,
                                                float* __restrict__ out) {
    __shared__ float Wrt[DD * DD];       // [o][i], 4 KB
    __shared__ float Wi[3 * DD * DD];    // [gate_row][i], 12 KB (native layout)
    __shared__ float Wh[3 * DD * DD];    // 12 KB
    __shared__ float bc[DD], bi[3 * DD], bh[3 * DD];
    int t = threadIdx.x;
    for (int i = t; i < DD * DD; i += 256) Wrt[(i & 31) * DD + (i >> 5)] = Wroot[i];
    for (int i = t; i < 3 * DD * DD; i += 256) { Wi[i] = Wih[i]; Wh[i] = Whh[i]; }
    if (t < DD) bc[t] = bconv[t];
    if (t < 3 * DD) { bi[t] = bih[t]; bh[t] = bhh[t]; }
    __syncthreads();

    int n = blockIdx.x * 256 + t;
    if (n >= N_NODES) return;

    float hr[DD], ag[DD];
    float4* hp = (float4*)(h + (size_t)n * DD);
    float4* ap = (float4*)(agg + (size_t)n * DD);
#pragma unroll
    for (int q = 0; q < DD / 4; ++q) { *(float4*)&hr[q * 4] = hp[q]; *(float4*)&ag[q * 4] = ap[q]; }
    float4 z4 = make_float4(0.f, 0.f, 0.f, 0.f);
#pragma unroll
    for (int q = 0; q < DD / 4; ++q) ap[q] = z4;   // agg := 0 for next step

    // conv = relu(agg + h @ Wroot + bconv)
    float cv[DD];
#pragma unroll
    for (int o = 0; o < DD; ++o) {
        const float4* wr = (const float4*)(Wrt + o * DD);
        float s = bc[o] + ag[o];
#pragma unroll
        for (int q = 0; q < DD / 4; ++q) {
            float4 wv = wr[q];
            s += hr[q * 4] * wv.x + hr[q * 4 + 1] * wv.y + hr[q * 4 + 2] * wv.z + hr[q * 4 + 3] * wv.w;
        }
        cv[o] = fmaxf(s, 0.f);
    }

    // GRU (gate order r, z, n)
    float hnew[DD];
#pragma unroll
    for (int o = 0; o < DD; ++o) {
        const float4* wir = (const float4*)(Wi + o * DD);
        const float4* wiz = (const float4*)(Wi + (DD + o) * DD);
        const float4* win = (const float4*)(Wi + (2 * DD + o) * DD);
        const float4* whr = (const float4*)(Wh + o * DD);
        const float4* whz = (const float4*)(Wh + (DD + o) * DD);
        const float4* whn = (const float4*)(Wh + (2 * DD + o) * DD);
        float gir = bi[o], giz = bi[DD + o], gin = bi[2 * DD + o];
        float ghr = bh[o], ghz = bh[DD + o], ghn = bh[2 * DD + o];
#pragma unroll
        for (int q = 0; q < DD / 4; ++q) {
            float4 c4 = *(const float4*)&cv[q * 4];
            float4 h4 = *(const float4*)&hr[q * 4];
            float4 a = wir[q], b = wiz[q], c = win[q];
            gir += c4.x * a.x + c4.y * a.y + c4.z * a.z + c4.w * a.w;
            giz += c4.x * b.x + c4.y * b.y + c4.z * b.z + c4.w * b.w;
            gin += c4.x * c.x + c4.y * c.y + c4.z * c.z + c4.w * c.w;
            float4 d = whr[q], e = whz[q], f = whn[q];
            ghr += h4.x * d.x + h4.y * d.y + h4.z * d.z + h4.w * d.w;
            ghz += h4.x * e.x + h4.y * e.y + h4.z * e.z + h4.w * e.w;
            ghn += h4.x * f.x + h4.y * f.y + h4.z * f.z + h4.w * f.w;
        }
        float r = 1.f / (1.f + expf(-(gir + ghr)));
        float z = 1.f / (1.f + expf(-(giz + ghz)));
        float nn = tanhf(gin + r * ghn);
        hnew[o] = (1.f - z) * nn + z * hr[o];
    }

    float4* op = out ? (float4*)(out + (size_t)n * DD) : nullptr;
#pragma unroll
    for (int q = 0; q < DD / 4; ++q) {
        float4 r4 = *(float4*)&hnew[q * 4];
        hp[q] = r4;
        if (op) op[q] = r4;
    }
}

// ---------------------------------------------------------------------------
extern "C" void kernel_launch(void* const* d_in, const int* in_sizes, int n_in,
                              void* d_out, int out_size, void* d_ws, size_t ws_size,
                              hipStream_t stream) {
    const float* x    = (const float*)d_in[0];
    const int*   ei   = (const int*)d_in[1];
    const float* ea   = (const float*)d_in[2];
    const float* Wn   = (const float*)d_in[3];
    const float* bn   = (const float*)d_in[4];
    const float* We1  = (const float*)d_in[5];
    const float* be1  = (const float*)d_in[6];
    const float* We2  = (const float*)d_in[7];
    const float* be2  = (const float*)d_in[8];
    const float* Wroot= (const float*)d_in[9];
    const float* bconv= (const float*)d_in[10];
    const float* Wih  = (const float*)d_in[11];
    const float* Whh  = (const float*)d_in[12];
    const float* bih  = (const float*)d_in[13];
    const float* bhh  = (const float*)d_in[14];
    float* out = (float*)d_out;   // fp32 output (device-verified)

    // ---- Workspace: 13.07 MB (proven-safe footprint) ----
    char* ws = (char*)d_ws;
    float*  h    = (float*)(ws);                    // 6.4 MB
    float*  agg  = (float*)(ws + 6400000);          // 6.4 MB
    ushort* we2B = (ushort*)(ws + 12800000);        // 256 KB fragment-major We2T
    ushort* we1B = (ushort*)(ws + 13062144);        // 8 KB   fragment-major We1T

    prep<<<66, 256, 0, stream>>>(We2, We1, we2B, we1B);
    node_init<<<(N_NODES + 255) / 256, 256, 0, stream>>>(x, Wn, bn, h);
    hipMemsetAsync(agg, 0, (size_t)N_NODES * DD * sizeof(float), stream);

    for (int step = 0; step < STEPS; ++step) {
        fused_msg<<<(N_EDGES + 255) / 256, 256, 0, stream>>>(ea, we1B, be1, we2B, be2,
                                                             ei, h, agg);
        conv_gru<<<(N_NODES + 255) / 256, 256, 0, stream>>>(agg, h, Wroot, bconv,
                                                            Wih, Whh, bih, bhh,
                                                            (step == STEPS - 1) ? out : nullptr);
    }
}

// Round 12
// 418.966 us; speedup vs baseline: 3.9384x; 3.9384x over previous
//
#include <hip/hip_runtime.h>
#include <hip/hip_bf16.h>

// Problem constants (from reference)
#define N_NODES 50000
#define N_EDGES 150000
#define NODE_IN 64
#define EDGE_IN 16
#define DD 32          // node feature dim
#define EHID 128       // edge-network hidden
#define STEPS 3

// Device-verified harness dtypes: float inputs fp32, edge_index int32, output fp32.
__device__ __forceinline__ ushort f2b(float f) {
    __hip_bfloat16 b = __float2bfloat16(f);   // RNE
    return *reinterpret_cast<ushort*>(&b);
}

typedef __bf16 bf16x8 __attribute__((ext_vector_type(8)));
typedef float  f32x4  __attribute__((ext_vector_type(4)));

#define LDA  136   // As leading dim (ushorts)
#define HPAD 36    // Hs leading dim (floats)

// ---------------------------------------------------------------------------
// prep: repack weights into MFMA-fragment-major bf16 buffers.
//  we2B: unit u = ((bn*4+nt)*4+kt)*64+lane -> bf16(We2[kt*32+lg*8+j][bn*64+nt*16+lr])
//  we1B: unit u = nt*64+lane -> bf16(We1[lg*8+j][nt*16+lr]), k>=16 -> 0
//  wgB : units 0..127   Wroot  B[n=o][k=i]  = Wroot[i][o]   (nt=u>>6, 2 tiles)
//        units 128..511 Wih^T  B[n=g][k=i]  = Wih[g][i]     (6 tiles)
//        units 512..895 Whh^T  B[n=g][k=i]  = Whh[g][i]     (6 tiles)
__global__ __launch_bounds__(256) void prep(const float* __restrict__ we2,
                                            const float* __restrict__ we1,
                                            const float* __restrict__ wroot,
                                            const float* __restrict__ wih,
                                            const float* __restrict__ whh,
                                            ushort* __restrict__ we2B,
                                            ushort* __restrict__ we1B,
                                            ushort* __restrict__ wgB) {
    int i = blockIdx.x * 256 + threadIdx.x;
    if (i < 16384) {
        int l = i & 63, f = i >> 6;           // f = bn*16 + nt*4 + kt
        int kt = f & 3, nt = (f >> 2) & 3, bn = f >> 4;
        int lr = l & 15, lg = l >> 4;
        int n = bn * 64 + nt * 16 + lr;
        int k0 = kt * 32 + lg * 8;
        ushort tmp[8];
#pragma unroll
        for (int j = 0; j < 8; ++j) tmp[j] = f2b(we2[(size_t)(k0 + j) * 1024 + n]);
        *(uint4*)(we2B + (size_t)i * 8) = *(uint4*)tmp;
    } else if (i < 16896) {
        int u = i - 16384;
        int l = u & 63, nt = u >> 6;
        int lr = l & 15, lg = l >> 4;
        int n = nt * 16 + lr;
        ushort tmp[8];
#pragma unroll
        for (int j = 0; j < 8; ++j) {
            int k = lg * 8 + j;
            tmp[j] = (k < EDGE_IN) ? f2b(we1[(size_t)k * EHID + n]) : (ushort)0;
        }
        *(uint4*)(we1B + (size_t)u * 8) = *(uint4*)tmp;
    } else if (i < 17792) {
        int u = i - 16896;
        int l = u & 63;
        int lr = l & 15, lg = l >> 4;
        ushort tmp[8];
        if (u < 128) {            // Wroot [i][o] row-major
            int nt = u >> 6;
#pragma unroll
            for (int j = 0; j < 8; ++j)
                tmp[j] = f2b(wroot[(size_t)(lg * 8 + j) * DD + nt * 16 + lr]);
        } else if (u < 512) {     // Wih [3D][D] row-major, B[n=gate-row][k=i]
            int nt = (u - 128) >> 6;
#pragma unroll
            for (int j = 0; j < 8; ++j)
                tmp[j] = f2b(wih[(size_t)(nt * 16 + lr) * DD + lg * 8 + j]);
        } else {                  // Whh
            int nt = (u - 512) >> 6;
#pragma unroll
            for (int j = 0; j < 8; ++j)
                tmp[j] = f2b(whh[(size_t)(nt * 16 + lr) * DD + lg * 8 + j]);
        }
        *(uint4*)(wgB + (size_t)u * 8) = *(uint4*)tmp;
    }
}

// ---------------------------------------------------------------------------
// node_init (round-10 proven form): thread = node, uniform LDS weight reads.
__global__ __launch_bounds__(256) void node_init(const float* __restrict__ x,
                                                 const float* __restrict__ Wn,
                                                 const float* __restrict__ bn,
                                                 float* __restrict__ h) {
    __shared__ float Wns[NODE_IN * DD];   // 8 KB
    __shared__ float bns[DD];
    int t = threadIdx.x;
    for (int i = t; i < NODE_IN * DD; i += 256) Wns[i] = Wn[i];
    if (t < DD) bns[t] = bn[t];
    __syncthreads();
    int n = blockIdx.x * 256 + t;
    if (n >= N_NODES) return;
    float xr[NODE_IN];
    const float4* xp = (const float4*)(x + (size_t)n * NODE_IN);
#pragma unroll
    for (int q = 0; q < NODE_IN / 4; ++q) *(float4*)&xr[q * 4] = xp[q];
    float out[DD];
#pragma unroll
    for (int o = 0; o < DD; ++o) {
        float s = bns[o];
#pragma unroll
        for (int i = 0; i < NODE_IN; ++i) s += xr[i] * Wns[i * DD + o];
        out[o] = fmaxf(s, 0.f);
    }
    float4* hp = (float4*)(h + (size_t)n * DD);
#pragma unroll
    for (int q = 0; q < DD / 4; ++q) hp[q] = *(float4*)&out[q * 4];
}

// ---------------------------------------------------------------------------
// fused_msg: block = 256 edges, 4 m-tiles per wave. B-frags stream from L2
// (fragment-major we2B); main loop barrier-free. Verified gfx950 16x16x32:
// A[m=lane&15][k=(lane>>4)*8+j], B[n=lane&15][k=same], D[row=(lane>>4)*4+r][col=lane&15].
__global__ __launch_bounds__(256, 2) void fused_msg(const float* __restrict__ ea,
                                                    const ushort* __restrict__ we1B,
                                                    const float* __restrict__ be1,
                                                    const ushort* __restrict__ we2B,
                                                    const float* __restrict__ be2,
                                                    const int* __restrict__ ei,
                                                    const float* __restrict__ h,
                                                    float* __restrict__ agg) {
    __shared__ __attribute__((aligned(16))) ushort AsHs[256 * LDA];  // 69632 B
    __shared__ float b1s[EHID];                                      // 512 B
    __shared__ float be2s[DD * DD];                                  // 4096 B
    float* Hs = (float*)AsHs;       // [256][HPAD] fp32 view, reused

    int t = threadIdx.x;
    if (t < EHID) b1s[t] = be1[t];
    for (int i = t; i < DD * DD; i += 256) be2s[i] = be2[i];

    int w = t >> 6, l = t & 63;
    int lr = l & 15, lg = l >> 4;

    // Phase A input fragments straight from global
    bf16x8 afe[4];
#pragma unroll
    for (int mi = 0; mi < 4; ++mi) {
        int e = blockIdx.x * 256 + (w * 4 + mi) * 16 + lr;
        ushort tmp[8] = {0, 0, 0, 0, 0, 0, 0, 0};
        if (lg < 2 && e < N_EDGES) {
            const float4* p = (const float4*)(ea + (size_t)e * EDGE_IN + lg * 8);
            float4 a = p[0], b = p[1];
            tmp[0] = f2b(a.x); tmp[1] = f2b(a.y); tmp[2] = f2b(a.z); tmp[3] = f2b(a.w);
            tmp[4] = f2b(b.x); tmp[5] = f2b(b.y); tmp[6] = f2b(b.z); tmp[7] = f2b(b.w);
        }
        afe[mi] = *(bf16x8*)tmp;
    }
    __syncthreads();   // (1) b1s ready

    // Phase A: g = relu(ea@We1+be1) via MFMA -> bf16 As[256][128]
#pragma unroll
    for (int nt = 0; nt < 8; ++nt) {
        bf16x8 bfe = *(const bf16x8*)(we1B + (size_t)((nt << 6) + l) * 8);
        int kh = nt * 16 + lr;
        float bb = b1s[kh];
#pragma unroll
        for (int mi = 0; mi < 4; ++mi) {
            f32x4 acc = (f32x4){0.f, 0.f, 0.f, 0.f};
            acc = __builtin_amdgcn_mfma_f32_16x16x32_bf16(afe[mi], bfe, acc, 0, 0, 0);
#pragma unroll
            for (int r = 0; r < 4; ++r)
                AsHs[((w * 4 + mi) * 16 + lg * 4 + r) * LDA + kh] = f2b(fmaxf(acc[r] + bb, 0.f));
        }
    }
    __syncthreads();   // (2) As complete

    bf16x8 afrag[4][4];
#pragma unroll
    for (int mi = 0; mi < 4; ++mi)
#pragma unroll
        for (int kt = 0; kt < 4; ++kt)
            afrag[mi][kt] = *(const bf16x8*)(&AsHs[((w * 4 + mi) * 16 + lr) * LDA + kt * 32 + lg * 8]);
    __syncthreads();   // (3) As reads done -> reuse as Hs

    // Gather h[src]: thread t owns edge row t
    {
        int e = blockIdx.x * 256 + t;
        float4* hd = (float4*)(Hs + t * HPAD);
        if (e < N_EDGES) {
            int src = ei[e];
            const float4* hr = (const float4*)(h + (size_t)src * DD);
#pragma unroll
            for (int q = 0; q < 8; ++q) hd[q] = hr[q];
        } else {
            float4 z = make_float4(0.f, 0.f, 0.f, 0.f);
#pragma unroll
            for (int q = 0; q < 8; ++q) hd[q] = z;
        }
    }
    __syncthreads();   // (4) Hs ready — last barrier

    float m_acc[4][4][2];
#pragma unroll
    for (int mi = 0; mi < 4; ++mi)
#pragma unroll
        for (int r = 0; r < 4; ++r) { m_acc[mi][r][0] = 0.f; m_acc[mi][r][1] = 0.f; }

    for (int bn = 0; bn < 16; ++bn) {
        float bv[4];
#pragma unroll
        for (int nt = 0; nt < 4; ++nt) bv[nt] = be2s[bn * 64 + nt * 16 + lr];

        f32x4 acc[4][4];
#pragma unroll
        for (int mi = 0; mi < 4; ++mi)
#pragma unroll
            for (int nt = 0; nt < 4; ++nt) acc[mi][nt] = (f32x4){0.f, 0.f, 0.f, 0.f};

#pragma unroll
        for (int kt = 0; kt < 4; ++kt) {
            const ushort* base = we2B + (size_t)((bn * 16 + kt) * 64 + l) * 8;
            bf16x8 b0 = *(const bf16x8*)(base);
            bf16x8 b1 = *(const bf16x8*)(base + 2048);
            bf16x8 b2 = *(const bf16x8*)(base + 4096);
            bf16x8 b3 = *(const bf16x8*)(base + 6144);
#pragma unroll
            for (int mi = 0; mi < 4; ++mi) {
                acc[mi][0] = __builtin_amdgcn_mfma_f32_16x16x32_bf16(afrag[mi][kt], b0, acc[mi][0], 0, 0, 0);
                acc[mi][1] = __builtin_amdgcn_mfma_f32_16x16x32_bf16(afrag[mi][kt], b1, acc[mi][1], 0, 0, 0);
                acc[mi][2] = __builtin_amdgcn_mfma_f32_16x16x32_bf16(afrag[mi][kt], b2, acc[mi][2], 0, 0, 0);
                acc[mi][3] = __builtin_amdgcn_mfma_f32_16x16x32_bf16(afrag[mi][kt], b3, acc[mi][3], 0, 0, 0);
            }
        }

        // Fold: col=bn*64+nt*16+lr -> i=2bn+(nt>>1), o=16*(nt&1)+lr
#pragma unroll
        for (int mi = 0; mi < 4; ++mi) {
#pragma unroll
            for (int r = 0; r < 4; ++r) {
                int row = (w * 4 + mi) * 16 + lg * 4 + r;
                float2 hv = *(const float2*)(Hs + row * HPAD + bn * 2);
#pragma unroll
                for (int nt = 0; nt < 4; ++nt) {
                    float hi = (nt >> 1) ? hv.y : hv.x;
                    m_acc[mi][r][nt & 1] += hi * (acc[mi][nt][r] + bv[nt]);
                }
            }
        }
    }

    // Scatter: agg[dst] += m
#pragma unroll
    for (int mi = 0; mi < 4; ++mi) {
#pragma unroll
        for (int r = 0; r < 4; ++r) {
            int le = (w * 4 + mi) * 16 + lg * 4 + r;
            int e = blockIdx.x * 256 + le;
            if (e < N_EDGES) {
                int dst = ei[N_EDGES + e];
                float* ar = agg + (size_t)dst * DD;
                atomicAdd(ar + lr,      m_acc[mi][r][0]);
                atomicAdd(ar + lr + 16, m_acc[mi][r][1]);
            }
        }
    }
}

// ---------------------------------------------------------------------------
// conv_gru (MFMA): block = 64 nodes, grid 782. conv = relu(agg + h@Wroot + bc)
// via 2 MFMA; gi = conv@Wih^T, gh = h@Whh^T via 12 MFMA; fp32 gates in D-layout.
// Weights come fragment-major from wgB. Zeroes agg after reading.
__global__ __launch_bounds__(256) void conv_gru(float* __restrict__ agg,
                                                float* __restrict__ h,
                                                const ushort* __restrict__ wgB,
                                                const float* __restrict__ bconv,
                                                const float* __restrict__ bih,
                                                const float* __restrict__ bhh,
                                                float* __restrict__ out) {
    __shared__ __attribute__((aligned(16))) ushort Ah[64 * 40];   // 5120 B
    __shared__ __attribute__((aligned(16))) ushort Ac[64 * 40];   // 5120 B
    __shared__ float hs[64 * 33];                                 // 8448 B
    __shared__ float bcs[DD], bis[3 * DD], bhs[3 * DD];
    int t = threadIdx.x;
    int base = blockIdx.x * 64;

    for (int idx = t; idx < 64 * DD; idx += 256) {
        int row = idx >> 5, col = idx & 31;
        int n = base + row;
        float v = (n < N_NODES) ? h[(size_t)n * DD + col] : 0.f;
        hs[row * 33 + col] = v;
        Ah[row * 40 + col] = f2b(v);
    }
    if (t < DD) bcs[t] = bconv[t];
    if (t < 3 * DD) { bis[t] = bih[t]; bhs[t] = bhh[t]; }
    __syncthreads();

    int w = t >> 6, l = t & 63;
    int lr = l & 15, lg = l >> 4;
    const f32x4 zro = (f32x4){0.f, 0.f, 0.f, 0.f};

    bf16x8 ah = *(const bf16x8*)(&Ah[(w * 16 + lr) * 40 + lg * 8]);

    // conv GEMM (2 n-tiles, K=32)
    f32x4 dcv[2];
#pragma unroll
    for (int nt = 0; nt < 2; ++nt) {
        bf16x8 b = *(const bf16x8*)(wgB + (size_t)(nt * 64 + l) * 8);
        dcv[nt] = __builtin_amdgcn_mfma_f32_16x16x32_bf16(ah, b, zro, 0, 0, 0);
    }
    // epilogue: + agg + bc, relu -> bf16 Ac; zero agg
#pragma unroll
    for (int nt = 0; nt < 2; ++nt) {
#pragma unroll
        for (int r = 0; r < 4; ++r) {
            int row = w * 16 + lg * 4 + r;
            int col = nt * 16 + lr;
            int n = base + row;
            float a = 0.f;
            if (n < N_NODES) {
                a = agg[(size_t)n * DD + col];
                agg[(size_t)n * DD + col] = 0.f;
            }
            Ac[row * 40 + col] = f2b(fmaxf(dcv[nt][r] + a + bcs[col], 0.f));
        }
    }
    __syncthreads();

    bf16x8 ac = *(const bf16x8*)(&Ac[(w * 16 + lr) * 40 + lg * 8]);

    // gate GEMMs: gi = conv@Wih^T (+bi), gh = h@Whh^T (+bh); 6 n-tiles each
    f32x4 gi[6], gh[6];
#pragma unroll
    for (int nt = 0; nt < 6; ++nt) {
        bf16x8 bi_ = *(const bf16x8*)(wgB + (size_t)(128 + nt * 64 + l) * 8);
        gi[nt] = __builtin_amdgcn_mfma_f32_16x16x32_bf16(ac, bi_, zro, 0, 0, 0);
        bf16x8 bh_ = *(const bf16x8*)(wgB + (size_t)(512 + nt * 64 + l) * 8);
        gh[nt] = __builtin_amdgcn_mfma_f32_16x16x32_bf16(ah, bh_, zro, 0, 0, 0);
    }

    // elementwise GRU in D-layout: col = gate*32 + ch*16 + lr -> tile gate*2+ch
#pragma unroll
    for (int r = 0; r < 4; ++r) {
        int row = w * 16 + lg * 4 + r;
        int n = base + row;
        if (n >= N_NODES) continue;
#pragma unroll
        for (int ch = 0; ch < 2; ++ch) {
            int o = ch * 16 + lr;
            float girv = gi[ch][r]     + bis[o];
            float gizv = gi[2 + ch][r] + bis[DD + o];
            float ginv = gi[4 + ch][r] + bis[2 * DD + o];
            float ghrv = gh[ch][r]     + bhs[o];
            float ghzv = gh[2 + ch][r] + bhs[DD + o];
            float ghnv = gh[4 + ch][r] + bhs[2 * DD + o];
            float R  = 1.f / (1.f + expf(-(girv + ghrv)));
            float Z  = 1.f / (1.f + expf(-(gizv + ghzv)));
            float Nn = tanhf(ginv + R * ghnv);
            float hold = hs[row * 33 + o];
            float hnew = (1.f - Z) * Nn + Z * hold;
            h[(size_t)n * DD + o] = hnew;
            if (out) out[(size_t)n * DD + o] = hnew;
        }
    }
}

// ---------------------------------------------------------------------------
extern "C" void kernel_launch(void* const* d_in, const int* in_sizes, int n_in,
                              void* d_out, int out_size, void* d_ws, size_t ws_size,
                              hipStream_t stream) {
    const float* x    = (const float*)d_in[0];
    const int*   ei   = (const int*)d_in[1];
    const float* ea   = (const float*)d_in[2];
    const float* Wn   = (const float*)d_in[3];
    const float* bn   = (const float*)d_in[4];
    const float* We1  = (const float*)d_in[5];
    const float* be1  = (const float*)d_in[6];
    const float* We2  = (const float*)d_in[7];
    const float* be2  = (const float*)d_in[8];
    const float* Wroot= (const float*)d_in[9];
    const float* bconv= (const float*)d_in[10];
    const float* Wih  = (const float*)d_in[11];
    const float* Whh  = (const float*)d_in[12];
    const float* bih  = (const float*)d_in[13];
    const float* bhh  = (const float*)d_in[14];
    float* out = (float*)d_out;   // fp32 output (device-verified)

    // ---- Workspace: within proven-safe 13.34 MB footprint ----
    char* ws = (char*)d_ws;
    float*  h    = (float*)(ws);                    // 6.4 MB
    float*  agg  = (float*)(ws + 6400000);          // 6.4 MB
    ushort* we2B = (ushort*)(ws + 12800000);        // 256 KB fragment-major We2T
    ushort* we1B = (ushort*)(ws + 13062144);        // 8 KB   fragment-major We1T
    ushort* wgB  = (ushort*)(ws + 13070336);        // 14 KB  fragment-major GRU weights

    prep<<<70, 256, 0, stream>>>(We2, We1, Wroot, Wih, Whh, we2B, we1B, wgB);
    node_init<<<(N_NODES + 255) / 256, 256, 0, stream>>>(x, Wn, bn, h);
    hipMemsetAsync(agg, 0, (size_t)N_NODES * DD * sizeof(float), stream);

    for (int step = 0; step < STEPS; ++step) {
        fused_msg<<<(N_EDGES + 255) / 256, 256, 0, stream>>>(ea, we1B, be1, we2B, be2,
                                                             ei, h, agg);
        conv_gru<<<(N_NODES + 63) / 64, 256, 0, stream>>>(agg, h, wgB, bconv, bih, bhh,
                                                          (step == STEPS - 1) ? out : nullptr);
    }
}